// Round 7
// baseline (74.324 us; speedup 1.0000x reference)
//
#include <hip/hip_runtime.h>

// BoxFilter: out = 9x9 box SUM of x with zero padding == reference
// diff_y(diff_x(cumsum_H(x),4).cumsum_W,4). fp32 in/out, 48 x 1024x1024.
//
// R7 = R6 with TILE 64 -> 32: grid 768 -> 1536 blocks (4 resident/CU, LDS-
// capped; 16 waves/CU vs 12). Tests MLP/barrier-coupling vs write-ceiling
// for the remaining gap (69.75 us vs ~63 us copy-floor).
// Carried from R6 (the 35us lever): 9-row register shift-history -> zero
// drop-row reloads; one lgkmcnt-only barrier per 4-row group; double-
// buffered vlds; NT stores.

#define RR 4
#define HH 1024
#define WW 1024
#define BLOCK 256
#define TILE 32
#define GROUP 4
#define NG (TILE / GROUP)
#define LDSW (WW + 2 * RR) // 1032

typedef float f32x4 __attribute__((ext_vector_type(4)));

__device__ __forceinline__ float4 zero4() {
    float4 z; z.x = 0.f; z.y = 0.f; z.z = 0.f; z.w = 0.f; return z;
}
__device__ __forceinline__ void add4(float4& a, const float4 b) {
    a.x += b.x; a.y += b.y; a.z += b.z; a.w += b.w;
}
__device__ __forceinline__ void accdiff(float4& a, const float4 b, const float4 c) {
    a.x += b.x - c.x; a.y += b.y - c.y; a.z += b.z - c.z; a.w += b.w - c.w;
}
__device__ __forceinline__ void nt_store4(float* p, const float4 o) {
    f32x4 t; t.x = o.x; t.y = o.y; t.z = o.z; t.w = o.w;
    __builtin_nontemporal_store(t, (f32x4*)p);
}

__global__ __launch_bounds__(BLOCK, 4) void box9_kernel(const float* __restrict__ x,
                                                        float* __restrict__ out) {
    const int tid = threadIdx.x;
    const int img = blockIdx.y;
    const int r0  = blockIdx.x * TILE;
    const size_t ioff = (size_t)img * HH * WW;
    const float* __restrict__ xi = x + ioff;
    float* __restrict__ oi       = out + ioff;
    const int c = 4 * tid;

    __shared__ float vlds[2][GROUP][LDSW];

    // constant zero column halos in both buffers (cols -4..-1, 1024..1027);
    // written once; drained by this wave's lgkmcnt(0) before the first barrier.
    if (tid < GROUP) {
#pragma unroll
        for (int p = 0; p < 2; ++p) {
            vlds[p][tid][0] = 0.f; vlds[p][tid][1] = 0.f;
            vlds[p][tid][2] = 0.f; vlds[p][tid][3] = 0.f;
            vlds[p][tid][LDSW - 4] = 0.f; vlds[p][tid][LDSW - 3] = 0.f;
            vlds[p][tid][LDSW - 2] = 0.f; vlds[p][tid][LDSW - 1] = 0.f;
        }
    }

    // history h[j] = x row (r0-4+j), j=0..8 (zero above the image);
    // v = vertical 9-sum at row r0; n = add rows r0+5..r0+8 (always valid,
    // r0 <= 992 so r0+8 <= 1000).
    float4 h[9], n[GROUP], m[GROUP], v = zero4();
#pragma unroll
    for (int j = 0; j < 9; ++j) {
        const int r = r0 - RR + j;
        h[j] = (r >= 0) ? *(const float4*)(xi + (size_t)r * WW + c) : zero4();
        add4(v, h[j]);
    }
#pragma unroll
    for (int k = 0; k < GROUP; ++k)
        n[k] = *(const float4*)(xi + (size_t)(r0 + RR + 1 + k) * WW + c);

    int p = 0;
    for (int g = 0; g < NG; ++g, p ^= 1) {
        const int b = r0 + g * GROUP;

        // ---- phase 1: issue next group's add rows, publish v-rows, advance.
        // h[0..3] are exactly drop rows b-4..b-1; no memory dependency.
#pragma unroll
        for (int k = 0; k < GROUP; ++k) { // rows b+9..b+12 (sole HBM read stream)
            const int rn = b + 2 * RR + 1 + k;
            m[k] = (rn < HH) ? *(const float4*)(xi + (size_t)rn * WW + c) : zero4();
        }
#pragma unroll
        for (int k = 0; k < GROUP; ++k) {
            *(float4*)(&vlds[p][k][4 + c]) = v;
            accdiff(v, n[k], h[k]);
        }
        asm volatile("s_waitcnt lgkmcnt(0)" ::: "memory"); // LDS visible; vmcnt NOT drained
        __builtin_amdgcn_s_barrier();

        // ---- phase 2: horizontal 9-tap sliding sum from LDS, NT store
#pragma unroll
        for (int k = 0; k < GROUP; ++k) {
            const float4 a0 = *(const float4*)(&vlds[p][k][c]);
            const float4 a1 = *(const float4*)(&vlds[p][k][c + 4]);
            const float4 a2 = *(const float4*)(&vlds[p][k][c + 8]);
            float4 o;
            o.x = a0.x + a0.y + a0.z + a0.w + a1.x + a1.y + a1.z + a1.w + a2.x;
            o.y = o.x - a0.x + a2.y;
            o.z = o.y - a0.y + a2.z;
            o.w = o.z - a0.z + a2.w;
            nt_store4(oi + (size_t)(b + k) * WW + c, o);
        }

        // ---- shift history by 4 rows (static indices -> stays in VGPRs)
#pragma unroll
        for (int j = 0; j < 5; ++j) h[j] = h[j + 4];
#pragma unroll
        for (int k = 0; k < GROUP; ++k) { h[5 + k] = n[k]; n[k] = m[k]; }
    }
}

extern "C" void kernel_launch(void* const* d_in, const int* in_sizes, int n_in,
                              void* d_out, int out_size, void* d_ws, size_t ws_size,
                              hipStream_t stream) {
    const float* x = (const float*)d_in[0];
    float* out     = (float*)d_out;
    const int nimg = in_sizes[0] / (HH * WW); // 48
    dim3 grid(HH / TILE, nimg, 1);            // (32, 48) = 1536 blocks
    box9_kernel<<<grid, BLOCK, 0, stream>>>(x, out);
}